// Round 12
// baseline (392.339 us; speedup 1.0000x reference)
//
#include <hip/hip_runtime.h>
#include <hip/hip_cooperative_groups.h>

namespace cg = cooperative_groups;

// Problem constants
#define B 8
#define N 4096
#define C 128
#define CL 128          // X row stride (lower-half features only)
#define KNN 21          // top-(K+1), drop nearest
#define CAP 22          // per-lane append buffer capacity (slots 0..21)

typedef unsigned long long u64;
typedef unsigned int u32;
typedef unsigned short u16;

typedef __attribute__((ext_vector_type(8))) short bf16x8;
typedef __attribute__((ext_vector_type(4))) float f32x4;

__device__ __forceinline__ float bf2f(u16 u) {
    return __uint_as_float(((u32)u) << 16);
}
__device__ __forceinline__ u16 f2bf(float f) {  // round-to-nearest-even
    u32 x = __float_as_uint(f);
    return (u16)((x + 0x7FFFu + ((x >> 16) & 1u)) >> 16);
}

// ---------------------------------------------------------------------------
// SINGLE COOPERATIVE KERNEL: phase 0 (transpose+lrelu+prepack) + grid sync +
// frozen r9 phases A-D. 512 blocks x 256 thr, 55KB LDS -> exactly 2 blocks/CU
// co-resident (LDS-limited), satisfying the cooperative-launch requirement.
//  0: block (b,n0) transposes its own 64-row X slice (float4 reads from pts,
//     16B/lane -- the old K1 read was 4B scalar), writes X (bf16x8) + its
//     cand[n0..n0+63] slice. __threadfence() + grid.sync() makes X/cand
//     device-visible (per-XCD L2 non-coherence handled by device-scope fence
//     + cooperative sync acquire). Same f2bf(lrelu) / sq_norm value sequence
//     bit-exact.
//  A: scan/compact BYTE-FOR-BYTE r3 (u32 sortable keys; core frozen after 8
//     failed variants).  B: 4-way merge.  C: gather straight into xs upper
//     half + stage lower half.  D: MFMA GEMM + epilogue (r9-proven).
// LDS overlays: 0: xt[64][132] u16 @0 (16896). A: stg 18432 | kbuf 22528 |
// ibuf 11264 = 52224. B: mg[256][21] u64 @0. C/D: xs[64][264] u16 @0.
// ---------------------------------------------------------------------------
__global__ __launch_bounds__(256) void k_all(
        float4* __restrict__ cand, u16* __restrict__ X,
        const float* __restrict__ Wc, const float* __restrict__ Wg,
        const float* __restrict__ pts, const float* __restrict__ bc,
        const float* __restrict__ bg, float* __restrict__ out,
        const float* __restrict__ xyz) {
    __shared__ __align__(16) char lds[52224];
    float4* stg  = (float4*)lds;                      // [4][288]  18432 B
    u32*    kbuf = (u32*)(lds + 18432);               // [CAP][256] 22528 B
    u16*    ibuf = (u16*)(lds + 18432 + 22528);       // [CAP][256] 11264 B
    u64*    mg   = (u64*)lds;                         // [256][21]  (phase B)
    u16 (*xs)[264] = (u16(*)[264])lds;                // [64][264]  (phase C/D)
    u16 (*xt)[132] = (u16(*)[132])lds;                // [64][132]  (phase 0)
    __shared__ u16 win[64 * KNN];

    int tid = threadIdx.x;
    int w = tid >> 6, l = tid & 63;
    int b = blockIdx.y;
    int n0 = blockIdx.x * 64;
    int nq = n0 + l;

    // ---- phase 0: transpose+lrelu this block's 64-n slice + cand slice
    {
        const float* src = pts + (size_t)b * C * N;
        #pragma unroll
        for (int it = 0; it < 8; ++it) {              // 128 c-rows, f32x4 reads
            int c  = it * 16 + (tid >> 4);            // 0..127
            int j4 = (tid & 15) * 4;                  // n offset, 16B aligned
            float4 v = *(const float4*)(src + (size_t)c * N + n0 + j4);
            float a0 = v.x, a1 = v.y, a2 = v.z, a3 = v.w;
            if (a0 < 0.f) a0 = __fmul_rn(a0, 0.01f);
            if (a1 < 0.f) a1 = __fmul_rn(a1, 0.01f);
            if (a2 < 0.f) a2 = __fmul_rn(a2, 0.01f);
            if (a3 < 0.f) a3 = __fmul_rn(a3, 0.01f);
            xt[j4 + 0][c] = f2bf(a0);
            xt[j4 + 1][c] = f2bf(a1);
            xt[j4 + 2][c] = f2bf(a2);
            xt[j4 + 3][c] = f2bf(a3);
        }
        if (tid < 64) {                               // cand prepack (64 pts)
            int n = n0 + tid;
            const float* xz = xyz + (size_t)b * 3 * N;
            float x = xz[n], y = xz[N + n], z = xz[2 * N + n];
            float sn = __fadd_rn(__fadd_rn(__fmul_rn(x, x), __fmul_rn(y, y)),
                                 __fmul_rn(z, z));
            cand[(size_t)b * N + n] = make_float4(x, y, z, sn);
        }
        __syncthreads();
        int r = tid >> 2, qtr = tid & 3;              // 64 rows x 4 x 64B
        u16* Xrow = X + (size_t)(b * N + n0 + r) * CL + qtr * 32;
        #pragma unroll
        for (int s = 0; s < 4; ++s)
            *(bf16x8*)(Xrow + s * 8) = *(const bf16x8*)(&xt[r][qtr * 32 + s * 8]);
    }
    __threadfence();                                  // device-scope release
    cg::this_grid().sync();                           // X & cand ready grid-wide

    const float4* candb = cand + (size_t)b * N;
    float4 cq = candb[nq];                            // query point (coalesced)
    float qx = cq.x, qy = cq.y, qz = cq.z, snq = cq.w;

    u32 key[KNN], idx[KNN];
    #pragma unroll
    for (int i = 0; i < KNN; ++i) { key[i] = 0xFFFFFFFFu; idx[i] = 0u; }
    int cnt = 0;
    u32 thr = 0xFFFFFFFFu;

    auto compact = [&]() {
        #pragma unroll 1
        for (int i = 0; i < CAP; ++i) {
            if (__ballot(i < cnt) == 0ull) break;
            u32 kv = kbuf[i * 256 + tid];
            u32 iv = ibuf[i * 256 + tid];
            bool ins = (i < cnt) && (kv < key[20]);   // strict: ties keep old
            if (__ballot(ins) != 0ull) {
                key[20] = ins ? kv : key[20];
                idx[20] = ins ? iv : idx[20];
                #pragma unroll
                for (int t = 19; t >= 0; --t) {       // stable bubble (strict >)
                    bool sw = key[t] > key[t + 1];
                    u32 ka = sw ? key[t + 1] : key[t];
                    u32 kz = sw ? key[t] : key[t + 1];
                    u32 ia = sw ? idx[t + 1] : idx[t];
                    u32 iz = sw ? idx[t] : idx[t + 1];
                    key[t] = ka; key[t + 1] = kz;
                    idx[t] = ia; idx[t + 1] = iz;
                }
            }
        }
        cnt = 0;
        thr = key[20];
    };

    float4* mystg = stg + w * 288;
    int wl = l + (l >> 3);                            // padded staging index

    for (int sc = 0; sc < 4; ++sc) {
        int m0 = w * 1024 + sc * 256;
        // stage 256 candidates from prepacked cand (coalesced float4)
        float4 v0 = candb[m0 + l];
        float4 v1 = candb[m0 + l + 64];
        float4 v2 = candb[m0 + l + 128];
        float4 v3 = candb[m0 + l + 192];
        mystg[wl]       = v0;                         // conflict-free writes
        mystg[wl + 72]  = v1;
        mystg[wl + 144] = v2;
        mystg[wl + 216] = v3;
        asm volatile("s_waitcnt lgkmcnt(0)" ::: "memory");
        for (int cc = 0; cc < 256; cc += 8) {
            int base = cc + (cc >> 3);                // wave-uniform padded base
            #pragma unroll
            for (int j = 0; j < 8; ++j) {
                float4 cp = mystg[base + j];          // wave-broadcast read
                int m = m0 + cc + j;
                float dot = __fadd_rn(__fadd_rn(__fmul_rn(qx, cp.x),
                                                __fmul_rn(qy, cp.y)),
                                      __fmul_rn(qz, cp.z));
                float sq = __fadd_rn(__fsub_rn(snq, __fadd_rn(dot, dot)), cp.w);
                u32 bits = __float_as_uint(sq);
                u32 kb = bits ^ (0x80000000u | (u32)(((int)bits) >> 31));
                kbuf[cnt * 256 + tid] = kb;           // unconditional append
                ibuf[cnt * 256 + tid] = (u16)m;
                cnt += (kb < thr);                    // strict: ties dropped
            }
            if (__ballot(cnt >= 15) != 0ull) compact();
        }
    }
    compact();

    __syncthreads();                                  // phase-A buffers dead
    #pragma unroll
    for (int j = 0; j < KNN; ++j)
        mg[(w * 64 + l) * KNN + j] = ((u64)key[j] << 32) | (u64)idx[j];
    __syncthreads();

    if (w == 0) {                                     // 4-way merge per query
        int p0 = 0, p1 = 0, p2 = 0, p3 = 0;
        for (int j = 0; j < KNN; ++j) {
            u64 c0 = mg[(0 * 64 + l) * KNN + p0];
            u64 c1 = mg[(1 * 64 + l) * KNN + p1];
            u64 c2 = mg[(2 * 64 + l) * KNN + p2];
            u64 c3 = mg[(3 * 64 + l) * KNN + p3];
            u64 m01 = c0 < c1 ? c0 : c1; int s01 = c0 < c1 ? 0 : 1;
            u64 m23 = c2 < c3 ? c2 : c3; int s23 = c2 < c3 ? 2 : 3;
            u64 mm = m01 < m23 ? m01 : m23;
            int sel = m01 < m23 ? s01 : s23;
            win[l * KNN + j] = (u16)(mm & 0xFFFFu);
            p0 += (sel == 0); p1 += (sel == 1); p2 += (sel == 2); p3 += (sel == 3);
        }
    }
    __syncthreads();                                  // win ready; mg dead

    // ---- phase C: stage xs lower half (coalesced) + gather-sum into upper
    const u16* Xb = X + (size_t)b * N * CL;
    #pragma unroll
    for (int it = 0; it < 4; ++it) {                  // 64 rows x 16 chunks
        int t = it * 256 + tid;                       // 0..1023
        int r = t >> 4, cch = t & 15;                 // row, 16B chunk
        *(bf16x8*)(&xs[r][cch * 8]) =
            *(const bf16x8*)(Xb + (size_t)(n0 + r) * CL + cch * 8);
    }
    for (int qq = 0; qq < 16; ++qq) {                 // wave w: 16 queries
        int q = w * 16 + qq;
        float f0 = 0.f, f1 = 0.f;
        #pragma unroll
        for (int j = 1; j < KNN; ++j) {               // skip nearest (j=0)
            int m = win[q * KNN + j];
            u32 u2 = *(const u32*)(Xb + (size_t)m * CL + 2 * l);
            f0 += bf2f((u16)(u2 & 0xFFFFu));
            f1 += bf2f((u16)(u2 >> 16));
        }
        *(u32*)(&xs[q][128 + 2 * l]) =                // straight into LDS
            ((u32)f2bf(f1) << 16) | (u32)f2bf(f0);
    }
    __syncthreads();                                  // xs panel complete

    // ---- phase D: MFMA body (wave w -> o rows w*32..w*32+31)
    int lane = tid & 63;
    int l16 = lane & 15, lq = lane >> 4;
    const float* wc0 = Wc + (size_t)(w * 32 + l16) * 128 + lq * 8;
    const float* wc1 = Wc + (size_t)(w * 32 + 16 + l16) * 128 + lq * 8;
    const float* wg0 = Wg + (size_t)(w * 32 + l16) * 128 + lq * 8;
    const float* wg1 = Wg + (size_t)(w * 32 + 16 + l16) * 128 + lq * 8;

    f32x4 acc[2][4];
    #pragma unroll
    for (int oo = 0; oo < 2; ++oo)
        #pragma unroll
        for (int t = 0; t < 4; ++t)
            acc[oo][t] = (f32x4){0.f, 0.f, 0.f, 0.f};

    #pragma unroll
    for (int kk = 0; kk < 8; ++kk) {
        const float* s0 = (kk < 4) ? (wc0 + kk * 32) : (wg0 + (kk - 4) * 32);
        const float* s1 = (kk < 4) ? (wc1 + kk * 32) : (wg1 + (kk - 4) * 32);
        float4 wa0 = *(const float4*)s0, wb0 = *(const float4*)(s0 + 4);
        float4 wa1 = *(const float4*)s1, wb1 = *(const float4*)(s1 + 4);
        bf16x8 a0, a1;
        a0[0] = (short)f2bf(wa0.x); a0[1] = (short)f2bf(wa0.y);
        a0[2] = (short)f2bf(wa0.z); a0[3] = (short)f2bf(wa0.w);
        a0[4] = (short)f2bf(wb0.x); a0[5] = (short)f2bf(wb0.y);
        a0[6] = (short)f2bf(wb0.z); a0[7] = (short)f2bf(wb0.w);
        a1[0] = (short)f2bf(wa1.x); a1[1] = (short)f2bf(wa1.y);
        a1[2] = (short)f2bf(wa1.z); a1[3] = (short)f2bf(wa1.w);
        a1[4] = (short)f2bf(wb1.x); a1[5] = (short)f2bf(wb1.y);
        a1[6] = (short)f2bf(wb1.z); a1[7] = (short)f2bf(wb1.w);
        #pragma unroll
        for (int t = 0; t < 4; ++t) {
            bf16x8 bt = *(const bf16x8*)(&xs[t * 16 + l16][lq * 8 + kk * 32]);
            acc[0][t] = __builtin_amdgcn_mfma_f32_16x16x32_bf16(a0, bt,
                                                                acc[0][t], 0, 0, 0);
            acc[1][t] = __builtin_amdgcn_mfma_f32_16x16x32_bf16(a1, bt,
                                                                acc[1][t], 0, 0, 0);
        }
    }

    const float inv21 = 1.0f / 21.0f;
    const float* pb = pts + (size_t)b * C * N;
    float* ob = out + (size_t)b * C * N;
    #pragma unroll
    for (int oo = 0; oo < 2; ++oo) {
        float bias[4];
        #pragma unroll
        for (int r = 0; r < 4; ++r) {
            int o = w * 32 + oo * 16 + lq * 4 + r;
            bias[r] = bc[o] + 20.f * bg[o];
        }
        #pragma unroll
        for (int t = 0; t < 4; ++t) {
            int n = n0 + t * 16 + l16;
            #pragma unroll
            for (int r = 0; r < 4; ++r) {
                int o = w * 32 + oo * 16 + lq * 4 + r;
                ob[(size_t)o * N + n] =
                    (acc[oo][t][r] + bias[r]) * inv21 + pb[(size_t)o * N + n];
            }
        }
    }
}

// ---------------------------------------------------------------------------
extern "C" void kernel_launch(void* const* d_in, const int* in_sizes, int n_in,
                              void* d_out, int out_size, void* d_ws, size_t ws_size,
                              hipStream_t stream) {
    const float* xyz = (const float*)d_in[0];
    const float* pts = (const float*)d_in[1];
    const float* Wc  = (const float*)d_in[2];
    const float* bc  = (const float*)d_in[3];
    const float* Wg  = (const float*)d_in[4];
    const float* bg  = (const float*)d_in[5];
    float* out = (float*)d_out;

    u16* X = (u16*)d_ws;                              // B*N*CL bf16 = 8 MB
    float4* cand = (float4*)((char*)d_ws +
                             (size_t)B * N * CL * sizeof(u16));  // +512 KB

    void* args[] = {(void*)&cand, (void*)&X, (void*)&Wc, (void*)&Wg,
                    (void*)&pts, (void*)&bc, (void*)&bg, (void*)&out,
                    (void*)&xyz};
    hipLaunchCooperativeKernel((void*)k_all, dim3(N / 64, B), dim3(256),
                               args, 0, stream);
}

// Round 13
// 268.273 us; speedup vs baseline: 1.4625x; 1.4625x over previous
//
#include <hip/hip_runtime.h>

// Problem constants
#define B 8
#define N 4096
#define C 128
#define CL 128          // X row stride (lower-half features only)
#define KNN 21          // top-(K+1), drop nearest
#define CAP 22          // per-lane append buffer capacity (slots 0..21)

typedef unsigned long long u64;
typedef unsigned int u32;
typedef unsigned short u16;

typedef __attribute__((ext_vector_type(8))) short bf16x8;
typedef __attribute__((ext_vector_type(4))) float f32x4;

__device__ __forceinline__ float bf2f(u16 u) {
    return __uint_as_float(((u32)u) << 16);
}
__device__ __forceinline__ u16 f2bf(float f) {  // round-to-nearest-even
    u32 x = __float_as_uint(f);
    return (u16)((x + 0x7FFFu + ((x >> 16) & 1u)) >> 16);
}

// ---------------------------------------------------------------------------
// K1: transpose + leaky_relu + cand prepack, 512-BLOCK GRID (was 4096: r12's
// accounting showed the old K1's ~55-60us envelope survived two write-path
// fixes -> grid/dispatch-structure-bound, 6KB work per tiny block). One block
// per (b, 64-n slab): float4 reads of pts rows (256B/16-lane group), lrelu +
// f2bf into LDS xt[64][132] (transpose), bf16x8 writes of X rows + coalesced
// cand float4 slice. Body identical to r12's correctness-proven phase 0.
// ---------------------------------------------------------------------------
__global__ __launch_bounds__(256) void k_prep(
        const float* __restrict__ pts, u16* __restrict__ X,
        const float* __restrict__ xyz, float4* __restrict__ cand) {
    __shared__ u16 xt[64][132];
    int b  = blockIdx.y;
    int n0 = blockIdx.x * 64;
    int tid = threadIdx.x;

    const float* src = pts + (size_t)b * C * N;
    #pragma unroll
    for (int it = 0; it < 8; ++it) {              // 128 c-rows, f32x4 reads
        int c  = it * 16 + (tid >> 4);            // 0..127
        int j4 = (tid & 15) * 4;                  // n offset, 16B aligned
        float4 v = *(const float4*)(src + (size_t)c * N + n0 + j4);
        float a0 = v.x, a1 = v.y, a2 = v.z, a3 = v.w;
        if (a0 < 0.f) a0 = __fmul_rn(a0, 0.01f);
        if (a1 < 0.f) a1 = __fmul_rn(a1, 0.01f);
        if (a2 < 0.f) a2 = __fmul_rn(a2, 0.01f);
        if (a3 < 0.f) a3 = __fmul_rn(a3, 0.01f);
        xt[j4 + 0][c] = f2bf(a0);
        xt[j4 + 1][c] = f2bf(a1);
        xt[j4 + 2][c] = f2bf(a2);
        xt[j4 + 3][c] = f2bf(a3);
    }
    if (tid < 64) {                               // cand prepack (64 pts)
        int n = n0 + tid;
        const float* xz = xyz + (size_t)b * 3 * N;
        float x = xz[n], y = xz[N + n], z = xz[2 * N + n];
        float sn = __fadd_rn(__fadd_rn(__fmul_rn(x, x), __fmul_rn(y, y)),
                             __fmul_rn(z, z));
        cand[(size_t)b * N + n] = make_float4(x, y, z, sn);
    }
    __syncthreads();
    int r = tid >> 2, qtr = tid & 3;              // 64 rows x 4 x 64B
    u16* Xrow = X + (size_t)(b * N + n0 + r) * CL + qtr * 32;
    #pragma unroll
    for (int s = 0; s < 4; ++s)
        *(bf16x8*)(Xrow + s * 8) = *(const bf16x8*)(&xt[r][qtr * 32 + s * 8]);
}

// ---------------------------------------------------------------------------
// K2 (FUSED): exact KNN + gather-sum + MFMA GEMM + epilogue, one block per
// (b, 64-query n-panel). FROZEN from r9/r11 (203-204us, proven): scan/compact
// r3 byte-for-byte; merge; gather straight into xs LDS upper half; MFMA body.
// ---------------------------------------------------------------------------
__global__ __launch_bounds__(256) void k_knn_gemm(
        const float4* __restrict__ cand, const u16* __restrict__ X,
        const float* __restrict__ Wc, const float* __restrict__ Wg,
        const float* __restrict__ pts, const float* __restrict__ bc,
        const float* __restrict__ bg, float* __restrict__ out) {
    __shared__ __align__(16) char lds[52224];
    float4* stg  = (float4*)lds;                      // [4][288]  18432 B
    u32*    kbuf = (u32*)(lds + 18432);               // [CAP][256] 22528 B
    u16*    ibuf = (u16*)(lds + 18432 + 22528);       // [CAP][256] 11264 B
    u64*    mg   = (u64*)lds;                         // [256][21]  (phase B)
    u16 (*xs)[264] = (u16(*)[264])lds;                // [64][264]  (phase C/D)
    __shared__ u16 win[64 * KNN];

    int tid = threadIdx.x;
    int w = tid >> 6, l = tid & 63;
    int b = blockIdx.y;
    int n0 = blockIdx.x * 64;
    int nq = n0 + l;

    const float4* candb = cand + (size_t)b * N;
    float4 cq = candb[nq];                            // query point (coalesced)
    float qx = cq.x, qy = cq.y, qz = cq.z, snq = cq.w;

    u32 key[KNN], idx[KNN];
    #pragma unroll
    for (int i = 0; i < KNN; ++i) { key[i] = 0xFFFFFFFFu; idx[i] = 0u; }
    int cnt = 0;
    u32 thr = 0xFFFFFFFFu;

    auto compact = [&]() {
        #pragma unroll 1
        for (int i = 0; i < CAP; ++i) {
            if (__ballot(i < cnt) == 0ull) break;
            u32 kv = kbuf[i * 256 + tid];
            u32 iv = ibuf[i * 256 + tid];
            bool ins = (i < cnt) && (kv < key[20]);   // strict: ties keep old
            if (__ballot(ins) != 0ull) {
                key[20] = ins ? kv : key[20];
                idx[20] = ins ? iv : idx[20];
                #pragma unroll
                for (int t = 19; t >= 0; --t) {       // stable bubble (strict >)
                    bool sw = key[t] > key[t + 1];
                    u32 ka = sw ? key[t + 1] : key[t];
                    u32 kz = sw ? key[t] : key[t + 1];
                    u32 ia = sw ? idx[t + 1] : idx[t];
                    u32 iz = sw ? idx[t] : idx[t + 1];
                    key[t] = ka; key[t + 1] = kz;
                    idx[t] = ia; idx[t + 1] = iz;
                }
            }
        }
        cnt = 0;
        thr = key[20];
    };

    float4* mystg = stg + w * 288;
    int wl = l + (l >> 3);                            // padded staging index

    for (int sc = 0; sc < 4; ++sc) {
        int m0 = w * 1024 + sc * 256;
        // stage 256 candidates from prepacked cand (coalesced float4)
        float4 v0 = candb[m0 + l];
        float4 v1 = candb[m0 + l + 64];
        float4 v2 = candb[m0 + l + 128];
        float4 v3 = candb[m0 + l + 192];
        mystg[wl]       = v0;                         // conflict-free writes
        mystg[wl + 72]  = v1;
        mystg[wl + 144] = v2;
        mystg[wl + 216] = v3;
        asm volatile("s_waitcnt lgkmcnt(0)" ::: "memory");
        for (int cc = 0; cc < 256; cc += 8) {
            int base = cc + (cc >> 3);                // wave-uniform padded base
            #pragma unroll
            for (int j = 0; j < 8; ++j) {
                float4 cp = mystg[base + j];          // wave-broadcast read
                int m = m0 + cc + j;
                float dot = __fadd_rn(__fadd_rn(__fmul_rn(qx, cp.x),
                                                __fmul_rn(qy, cp.y)),
                                      __fmul_rn(qz, cp.z));
                float sq = __fadd_rn(__fsub_rn(snq, __fadd_rn(dot, dot)), cp.w);
                u32 bits = __float_as_uint(sq);
                u32 kb = bits ^ (0x80000000u | (u32)(((int)bits) >> 31));
                kbuf[cnt * 256 + tid] = kb;           // unconditional append
                ibuf[cnt * 256 + tid] = (u16)m;
                cnt += (kb < thr);                    // strict: ties dropped
            }
            if (__ballot(cnt >= 15) != 0ull) compact();
        }
    }
    compact();

    __syncthreads();                                  // phase-A buffers dead
    #pragma unroll
    for (int j = 0; j < KNN; ++j)
        mg[(w * 64 + l) * KNN + j] = ((u64)key[j] << 32) | (u64)idx[j];
    __syncthreads();

    if (w == 0) {                                     // 4-way merge per query
        int p0 = 0, p1 = 0, p2 = 0, p3 = 0;
        for (int j = 0; j < KNN; ++j) {
            u64 c0 = mg[(0 * 64 + l) * KNN + p0];
            u64 c1 = mg[(1 * 64 + l) * KNN + p1];
            u64 c2 = mg[(2 * 64 + l) * KNN + p2];
            u64 c3 = mg[(3 * 64 + l) * KNN + p3];
            u64 m01 = c0 < c1 ? c0 : c1; int s01 = c0 < c1 ? 0 : 1;
            u64 m23 = c2 < c3 ? c2 : c3; int s23 = c2 < c3 ? 2 : 3;
            u64 mm = m01 < m23 ? m01 : m23;
            int sel = m01 < m23 ? s01 : s23;
            win[l * KNN + j] = (u16)(mm & 0xFFFFu);
            p0 += (sel == 0); p1 += (sel == 1); p2 += (sel == 2); p3 += (sel == 3);
        }
    }
    __syncthreads();                                  // win ready; mg dead

    // ---- phase C: stage xs lower half (coalesced) + gather-sum into upper
    const u16* Xb = X + (size_t)b * N * CL;
    #pragma unroll
    for (int it = 0; it < 4; ++it) {                  // 64 rows x 16 chunks
        int t = it * 256 + tid;                       // 0..1023
        int r = t >> 4, cch = t & 15;                 // row, 16B chunk
        *(bf16x8*)(&xs[r][cch * 8]) =
            *(const bf16x8*)(Xb + (size_t)(n0 + r) * CL + cch * 8);
    }
    for (int qq = 0; qq < 16; ++qq) {                 // wave w: 16 queries
        int q = w * 16 + qq;
        float f0 = 0.f, f1 = 0.f;
        #pragma unroll
        for (int j = 1; j < KNN; ++j) {               // skip nearest (j=0)
            int m = win[q * KNN + j];
            u32 u2 = *(const u32*)(Xb + (size_t)m * CL + 2 * l);
            f0 += bf2f((u16)(u2 & 0xFFFFu));
            f1 += bf2f((u16)(u2 >> 16));
        }
        *(u32*)(&xs[q][128 + 2 * l]) =                // straight into LDS
            ((u32)f2bf(f1) << 16) | (u32)f2bf(f0);
    }
    __syncthreads();                                  // xs panel complete

    // ---- phase D: MFMA body (wave w -> o rows w*32..w*32+31)
    int lane = tid & 63;
    int l16 = lane & 15, lq = lane >> 4;
    const float* wc0 = Wc + (size_t)(w * 32 + l16) * 128 + lq * 8;
    const float* wc1 = Wc + (size_t)(w * 32 + 16 + l16) * 128 + lq * 8;
    const float* wg0 = Wg + (size_t)(w * 32 + l16) * 128 + lq * 8;
    const float* wg1 = Wg + (size_t)(w * 32 + 16 + l16) * 128 + lq * 8;

    f32x4 acc[2][4];
    #pragma unroll
    for (int oo = 0; oo < 2; ++oo)
        #pragma unroll
        for (int t = 0; t < 4; ++t)
            acc[oo][t] = (f32x4){0.f, 0.f, 0.f, 0.f};

    #pragma unroll
    for (int kk = 0; kk < 8; ++kk) {
        const float* s0 = (kk < 4) ? (wc0 + kk * 32) : (wg0 + (kk - 4) * 32);
        const float* s1 = (kk < 4) ? (wc1 + kk * 32) : (wg1 + (kk - 4) * 32);
        float4 wa0 = *(const float4*)s0, wb0 = *(const float4*)(s0 + 4);
        float4 wa1 = *(const float4*)s1, wb1 = *(const float4*)(s1 + 4);
        bf16x8 a0, a1;
        a0[0] = (short)f2bf(wa0.x); a0[1] = (short)f2bf(wa0.y);
        a0[2] = (short)f2bf(wa0.z); a0[3] = (short)f2bf(wa0.w);
        a0[4] = (short)f2bf(wb0.x); a0[5] = (short)f2bf(wb0.y);
        a0[6] = (short)f2bf(wb0.z); a0[7] = (short)f2bf(wb0.w);
        a1[0] = (short)f2bf(wa1.x); a1[1] = (short)f2bf(wa1.y);
        a1[2] = (short)f2bf(wa1.z); a1[3] = (short)f2bf(wa1.w);
        a1[4] = (short)f2bf(wb1.x); a1[5] = (short)f2bf(wb1.y);
        a1[6] = (short)f2bf(wb1.z); a1[7] = (short)f2bf(wb1.w);
        #pragma unroll
        for (int t = 0; t < 4; ++t) {
            bf16x8 bt = *(const bf16x8*)(&xs[t * 16 + l16][lq * 8 + kk * 32]);
            acc[0][t] = __builtin_amdgcn_mfma_f32_16x16x32_bf16(a0, bt,
                                                                acc[0][t], 0, 0, 0);
            acc[1][t] = __builtin_amdgcn_mfma_f32_16x16x32_bf16(a1, bt,
                                                                acc[1][t], 0, 0, 0);
        }
    }

    const float inv21 = 1.0f / 21.0f;
    const float* pb = pts + (size_t)b * C * N;
    float* ob = out + (size_t)b * C * N;
    #pragma unroll
    for (int oo = 0; oo < 2; ++oo) {
        float bias[4];
        #pragma unroll
        for (int r = 0; r < 4; ++r) {
            int o = w * 32 + oo * 16 + lq * 4 + r;
            bias[r] = bc[o] + 20.f * bg[o];
        }
        #pragma unroll
        for (int t = 0; t < 4; ++t) {
            int n = n0 + t * 16 + l16;
            #pragma unroll
            for (int r = 0; r < 4; ++r) {
                int o = w * 32 + oo * 16 + lq * 4 + r;
                ob[(size_t)o * N + n] =
                    (acc[oo][t][r] + bias[r]) * inv21 + pb[(size_t)o * N + n];
            }
        }
    }
}

// ---------------------------------------------------------------------------
extern "C" void kernel_launch(void* const* d_in, const int* in_sizes, int n_in,
                              void* d_out, int out_size, void* d_ws, size_t ws_size,
                              hipStream_t stream) {
    const float* xyz = (const float*)d_in[0];
    const float* pts = (const float*)d_in[1];
    const float* Wc  = (const float*)d_in[2];
    const float* bc  = (const float*)d_in[3];
    const float* Wg  = (const float*)d_in[4];
    const float* bg  = (const float*)d_in[5];
    float* out = (float*)d_out;

    u16* X = (u16*)d_ws;                              // B*N*CL bf16 = 8 MB
    float4* cand = (float4*)((char*)d_ws +
                             (size_t)B * N * CL * sizeof(u16));  // +512 KB

    k_prep<<<dim3(N / 64, B), dim3(256), 0, stream>>>(pts, X, xyz, cand);
    k_knn_gemm<<<dim3(N / 64, B), dim3(256), 0, stream>>>(
        cand, X, Wc, Wg, pts, bc, bg, out);
}